// Round 2
// baseline (384.282 us; speedup 1.0000x reference)
//
#include <hip/hip_runtime.h>
#include <math.h>

typedef unsigned short u16;
typedef __attribute__((ext_vector_type(8))) short bf16x8;
typedef __attribute__((ext_vector_type(4))) float f32x4;
typedef __attribute__((ext_vector_type(16))) float f32x16;

// workspace layout (bf16 elements)
constexpr int OFF_W1 = 0;          // [3][128][128]  (l, h, c)
constexpr int OFF_W2 = 49152;      // [3][128][128]  (l, c, h)
constexpr int OFF_GW = 98304;      // [256][128]     (o, h)
constexpr int OFF_TG = 131072;     // [64][16]  rows>=42 / cols>=9 zero
constexpr int OFF_FG = 132096;     // [32][48]  rows>=9  / cols>=42 zero
constexpr int WS_ELEMS = 133632;   // bytes needed in d_ws = 267264

__device__ __forceinline__ u16 f2bf(float f) {
    unsigned u = __float_as_uint(f);
    u += 0x7FFFu + ((u >> 16) & 1u);   // RNE
    return (u16)(u >> 16);
}

__global__ void prep_kernel(const float* __restrict__ w1, const float* __restrict__ gw,
                            const float* __restrict__ w2, const float* __restrict__ tg,
                            const float* __restrict__ fg, u16* __restrict__ wsb) {
    const int idx = blockIdx.x * blockDim.x + threadIdx.x;
    const int str = gridDim.x * blockDim.x;
    for (int i = idx; i < 49152; i += str) wsb[OFF_W1 + i] = f2bf(w1[i]);
    for (int i = idx; i < 49152; i += str) wsb[OFF_W2 + i] = f2bf(w2[i]);
    for (int i = idx; i < 32768; i += str) wsb[OFF_GW + i] = f2bf(gw[i]);
    for (int i = idx; i < 1024; i += str) {
        int a = i >> 4, k = i & 15;
        wsb[OFF_TG + i] = (a < 42 && k < 9) ? f2bf(tg[a * 9 + k]) : (u16)0;
    }
    for (int i = idx; i < 1536; i += str) {
        int m = i / 48, k = i - m * 48;
        wsb[OFF_FG + i] = (m < 9 && k < 42) ? f2bf(fg[m * 42 + k]) : (u16)0;
    }
}

// 4 nodes per 256-thread WG.  LDS 53504 B -> 3 WG/CU (160 KiB / 3 = 54613 B).
// batched-row layout (64 rows): l0: rows 0..3 (node), l1: 16+n*3+mm, l2: 32+n*5+mm
__global__ __launch_bounds__(256, 3) void eqffn_mfma(
    const float* __restrict__ x, const float* __restrict__ nw,
    const float* __restrict__ b1f, const float* __restrict__ gbf,
    const float* __restrict__ b2f, const u16* __restrict__ wsb,
    float* __restrict__ out, int N)
{
    __shared__ u16 sh_a1[64 * 136];   // A1 (packed norm acts), later h2b (union)  17408 B
    __shared__ u16 sh_h1T[128 * 20];  // CURRENT node only: [h][m-pad20]; cols 9..19 zero  5120 B
    __shared__ u16 sh_g[48 * 136];    // per-node grid acts [a][h]                 13056 B
    __shared__ u16 sh_g2T[128 * 56];  // per-node swiglu out [o][a-pad56]; cols 42..47 zero  14336 B
    __shared__ float sh_nw[384];
    __shared__ float sh_b1[128];
    __shared__ float sh_b2[128];
    __shared__ float sh_gb[256];

    const int tid  = threadIdx.x;
    const int w    = tid >> 6;       // wave id
    const int lane = tid & 63;
    const int q    = lane >> 4;      // 16x16 quad
    const int r    = lane & 15;
    const int r32  = lane & 31;      // 32x32 row/col
    const int half = lane >> 5;
    const int n0   = blockIdx.x * 4;

    // ---- small hoisted weight fragments (L2-resident) ----
    const bf16x8 tgA0 = *(const bf16x8*)&wsb[OFF_TG + r32 * 16 + half * 8];
    const bf16x8 tgA1 = *(const bf16x8*)&wsb[OFF_TG + (32 + r32) * 16 + half * 8];
    bf16x8 fgA[3];
    #pragma unroll
    for (int k = 0; k < 3; ++k)
        fgA[k] = *(const bf16x8*)&wsb[OFF_FG + r32 * 48 + k * 16 + half * 8];

    // ---- init: stage small vectors, zero padded LDS regions ----
    for (int i = tid; i < 384; i += 256) sh_nw[i] = nw[i];
    if (tid < 128) { sh_b1[tid] = b1f[tid]; sh_b2[tid] = b2f[tid]; }
    sh_gb[tid] = gbf[tid];
    {
        unsigned long long* z1 = (unsigned long long*)sh_h1T;
        for (int i = tid; i < 640; i += 256) z1[i] = 0ull;
        unsigned long long* z2 = (unsigned long long*)sh_g2T;
        for (int i = tid; i < 1792; i += 256) z2[i] = 0ull;
    }
    __syncthreads();

    // ---- phase A: load x (wave w -> node n0+w), RMS, pack+normalize -> A1 bf16 ----
    const int myn = n0 + w;
    float4 xv[5];
    float ss = 0.f;
    if (myn < N) {
        const float4* xr = (const float4*)(x + (size_t)myn * 1152);
        for (int i = lane, c2 = 0; i < 288; i += 64, ++c2) {
            float4 v = xr[i]; xv[c2] = v;
            ss += v.x * v.x + v.y * v.y + v.z * v.z + v.w * v.w;
        }
    }
    #pragma unroll
    for (int off = 32; off; off >>= 1) ss += __shfl_xor(ss, off);
    const float inv = 1.0f / sqrtf(ss * (1.0f / 1152.0f) + 1e-6f);
    if (myn < N) {
        for (int i = lane, c2 = 0; i < 288; i += 64, ++c2) {
            float4 v = xv[c2];
            #pragma unroll
            for (int e = 0; e < 4; ++e) {
                const int f = i * 4 + e;
                const float val = ((const float*)&v)[e] * inv;
                int row, c, l;
                if (f < 128)      { l = 0; c = f;            row = w; }
                else if (f < 512) { int t = f - 128; l = 1; c = t / 3; row = 16 + w * 3 + (t - c * 3); }
                else              { int t = f - 512; l = 2; c = t / 5; row = 32 + w * 5 + (t - c * 5); }
                sh_a1[row * 136 + c] = f2bf(val * sh_nw[l * 128 + c]);
            }
        }
    }
    __syncthreads();

    // ---- GEMM1 (batched, 16x16x32): h1[row][h] = sum_c A1[row][c] w1[l][h][c] ----
    // accumulators stay in registers; per-node slices are written to LDS inside the loop.
    f32x4 acc1[4][2];
    {
        #pragma unroll
        for (int a = 0; a < 4; ++a)
            #pragma unroll
            for (int b = 0; b < 2; ++b)
                #pragma unroll
                for (int e = 0; e < 4; ++e) acc1[a][b][e] = 0.f;
        #pragma unroll
        for (int mt = 0; mt < 4; ++mt) {
            const int l = (mt == 0) ? 0 : ((mt == 1) ? 1 : 2);
            #pragma unroll
            for (int k = 0; k < 4; ++k) {
                bf16x8 af = *(const bf16x8*)&sh_a1[(mt * 16 + r) * 136 + k * 32 + q * 8];
                #pragma unroll
                for (int nt = 0; nt < 2; ++nt) {
                    const int h = (2 * w + nt) * 16 + r;
                    bf16x8 bf = *(const bf16x8*)&wsb[OFF_W1 + (l * 128 + h) * 128 + k * 32 + q * 8];
                    acc1[mt][nt] = __builtin_amdgcn_mfma_f32_16x16x32_bf16(af, bf, acc1[mt][nt], 0, 0, 0);
                }
            }
        }
    }
    // NOTE: no barrier here.  The first barrier inside the loop (after to_grid)
    // guarantees all waves finished their GEMM1 sh_a1 reads before any
    // from_grid write into sh_a1.

    // ---- per-node grid pipeline ----
    for (int nn = 0; nn < 4; ++nn) {
        // write h1T slice for node nn from held acc1 (wave-local: wave w owns h in [32w,32w+32))
        #pragma unroll
        for (int mt = 0; mt < 4; ++mt) {
            #pragma unroll
            for (int nt = 0; nt < 2; ++nt) {
                const int h = (2 * w + nt) * 16 + r;
                #pragma unroll
                for (int rg = 0; rg < 4; ++rg) {
                    const int rr = q * 4 + rg;
                    const float v = acc1[mt][nt][rg];
                    if (mt == 0) {
                        if (rr == nn) sh_h1T[h * 20 + 0] = f2bf(v + sh_b1[h]);
                    } else if (mt == 1) {
                        if (rr >= 3 * nn && rr < 3 * nn + 3) sh_h1T[h * 20 + 1 + (rr - 3 * nn)] = f2bf(v);
                    } else {
                        const int rr2 = (mt - 2) * 16 + rr;
                        if (rr2 >= 5 * nn && rr2 < 5 * nn + 5) sh_h1T[h * 20 + 4 + (rr2 - 5 * nn)] = f2bf(v);
                    }
                }
            }
        }

        // to_grid (32x32x16): g[a][h] = sum_m tg[a][m] h1[m][h]; wave w -> h block w*32
        // h1T read is wave-local (same rows we just wrote) -> compiler lgkmcnt, no barrier.
        {
            bf16x8 bfn = *(const bf16x8*)&sh_h1T[(w * 32 + r32) * 20 + half * 8];
            f32x16 ac0, ac1;
            #pragma unroll
            for (int e = 0; e < 16; ++e) { ac0[e] = 0.f; ac1[e] = 0.f; }
            ac0 = __builtin_amdgcn_mfma_f32_32x32x16_bf16(tgA0, bfn, ac0, 0, 0, 0);
            ac1 = __builtin_amdgcn_mfma_f32_32x32x16_bf16(tgA1, bfn, ac1, 0, 0, 0);
            const int h = w * 32 + r32;
            #pragma unroll
            for (int rg = 0; rg < 16; ++rg) {
                const int ar = (rg & 3) + 8 * (rg >> 2) + 4 * half;
                sh_g[ar * 136 + h] = f2bf(ac0[rg]);
                const int ar1 = 32 + ar;
                if (ar1 < 48) sh_g[ar1 * 136 + h] = f2bf(ac1[rg]);
            }
        }
        __syncthreads();   // g ready for all waves (also releases sh_a1 GEMM1 reads on nn==0)

        bf16x8 bfr[3][4];
        #pragma unroll
        for (int nt = 0; nt < 3; ++nt)
            #pragma unroll
            for (int k = 0; k < 4; ++k)
                bfr[nt][k] = *(const bf16x8*)&sh_g[(nt * 16 + r) * 136 + k * 32 + q * 8];
        __syncthreads();   // all g reads complete -> next iter may overwrite sh_g

        // SwiGLU (transposed, 16x16x32): zT[o][a] = sum_h gw[o][h] g[a][h]
        f32x4 aL[2][3], aH[2][3];
        #pragma unroll
        for (int p = 0; p < 2; ++p)
            #pragma unroll
            for (int nt = 0; nt < 3; ++nt)
                #pragma unroll
                for (int e = 0; e < 4; ++e) { aL[p][nt][e] = 0.f; aH[p][nt][e] = 0.f; }
        #pragma unroll
        for (int p = 0; p < 2; ++p) {
            const int oL = (2 * w + p) * 16 + r;
            #pragma unroll
            for (int k = 0; k < 4; ++k) {
                bf16x8 fL = *(const bf16x8*)&wsb[OFF_GW + oL * 128 + k * 32 + q * 8];
                bf16x8 fH = *(const bf16x8*)&wsb[OFF_GW + (oL + 128) * 128 + k * 32 + q * 8];
                #pragma unroll
                for (int nt = 0; nt < 3; ++nt) {
                    aL[p][nt] = __builtin_amdgcn_mfma_f32_16x16x32_bf16(fL, bfr[nt][k], aL[p][nt], 0, 0, 0);
                    aH[p][nt] = __builtin_amdgcn_mfma_f32_16x16x32_bf16(fH, bfr[nt][k], aH[p][nt], 0, 0, 0);
                }
            }
        }
        // silu epilogue -> g2T[o][a] (rows o = w*32..w*32+31: wave-local)
        #pragma unroll
        for (int p = 0; p < 2; ++p) {
            #pragma unroll
            for (int nt = 0; nt < 3; ++nt) {
                #pragma unroll
                for (int rg = 0; rg < 4; ++rg) {
                    const int o = (2 * w + p) * 16 + q * 4 + rg;
                    const int a = nt * 16 + r;
                    const float zl = aL[p][nt][rg] + sh_gb[o];
                    const float zh = aH[p][nt][rg] + sh_gb[128 + o];
                    const float gv = zl * (1.0f / (1.0f + __expf(-zl))) * zh;
                    if (a < 42) sh_g2T[o * 56 + a] = f2bf(gv);
                }
            }
        }

        // from_grid (32x32x16, K=48, wave-local rows of g2T): h2[m][h] = sum_a fg[m][a] g2T[h][a]
        {
            f32x16 ac;
            #pragma unroll
            for (int e = 0; e < 16; ++e) ac[e] = 0.f;
            const int h = w * 32 + r32;
            #pragma unroll
            for (int k = 0; k < 3; ++k) {
                bf16x8 bv = *(const bf16x8*)&sh_g2T[h * 56 + k * 16 + half * 8];
                ac = __builtin_amdgcn_mfma_f32_32x32x16_bf16(fgA[k], bv, ac, 0, 0, 0);
            }
            #pragma unroll
            for (int rg = 0; rg < 16; ++rg) {
                const int m = (rg & 3) + 8 * (rg >> 2) + 4 * half;
                if (m < 9) {
                    const int row = (m == 0) ? nn : ((m < 4) ? (16 + nn * 3 + (m - 1)) : (32 + nn * 5 + (m - 4)));
                    sh_a1[row * 136 + h] = f2bf(ac[rg]);
                }
            }
        }
    }
    __syncthreads();

    // ---- GEMM2 (batched, 16x16x32) + bias + unpack scatter store ----
    {
        f32x4 acc[4][2];
        #pragma unroll
        for (int a = 0; a < 4; ++a)
            #pragma unroll
            for (int b = 0; b < 2; ++b)
                #pragma unroll
                for (int e = 0; e < 4; ++e) acc[a][b][e] = 0.f;
        #pragma unroll
        for (int mt = 0; mt < 4; ++mt) {
            const int l = (mt == 0) ? 0 : ((mt == 1) ? 1 : 2);
            #pragma unroll
            for (int k = 0; k < 4; ++k) {
                bf16x8 af = *(const bf16x8*)&sh_a1[(mt * 16 + r) * 136 + k * 32 + q * 8];
                #pragma unroll
                for (int nt = 0; nt < 2; ++nt) {
                    const int c = (2 * w + nt) * 16 + r;
                    bf16x8 bf = *(const bf16x8*)&wsb[OFF_W2 + (l * 128 + c) * 128 + k * 32 + q * 8];
                    acc[mt][nt] = __builtin_amdgcn_mfma_f32_16x16x32_bf16(af, bf, acc[mt][nt], 0, 0, 0);
                }
            }
        }
        #pragma unroll
        for (int mt = 0; mt < 4; ++mt) {
            #pragma unroll
            for (int nt = 0; nt < 2; ++nt) {
                const int c = (2 * w + nt) * 16 + r;
                #pragma unroll
                for (int rg = 0; rg < 4; ++rg) {
                    const int rr = q * 4 + rg;
                    const float v = acc[mt][nt][rg];
                    if (mt == 0) {
                        if (rr < 4) { int gn = n0 + rr; if (gn < N) out[(size_t)gn * 1152 + c] = v + sh_b2[c]; }
                    } else if (mt == 1) {
                        if (rr < 12) { int nd = rr / 3, mm = rr - nd * 3; int gn = n0 + nd;
                                       if (gn < N) out[(size_t)gn * 1152 + 128 + c * 3 + mm] = v; }
                    } else {
                        int rr2 = (mt - 2) * 16 + rr;
                        if (rr2 < 20) { int nd = rr2 / 5, mm = rr2 - nd * 5; int gn = n0 + nd;
                                        if (gn < N) out[(size_t)gn * 1152 + 512 + c * 5 + mm] = v; }
                    }
                }
            }
        }
    }
}

extern "C" void kernel_launch(void* const* d_in, const int* in_sizes, int n_in,
                              void* d_out, int out_size, void* d_ws, size_t ws_size,
                              hipStream_t stream)
{
    const float* x  = (const float*)d_in[0];
    const float* nw = (const float*)d_in[1];
    const float* w1 = (const float*)d_in[2];
    const float* b1 = (const float*)d_in[3];
    const float* gw = (const float*)d_in[4];
    const float* gb = (const float*)d_in[5];
    const float* w2 = (const float*)d_in[6];
    const float* b2 = (const float*)d_in[7];
    const float* tg = (const float*)d_in[8];
    const float* fg = (const float*)d_in[9];
    float* out = (float*)d_out;
    u16* wsb = (u16*)d_ws;

    const int N = in_sizes[0] / 1152;
    prep_kernel<<<64, 256, 0, stream>>>(w1, gw, w2, tg, fg, wsb);
    eqffn_mfma<<<(N + 3) / 4, 256, 0, stream>>>(x, nw, b1, gb, b2, wsb, out, N);
}

// Round 3
// 348.153 us; speedup vs baseline: 1.1038x; 1.1038x over previous
//
#include <hip/hip_runtime.h>
#include <math.h>

typedef unsigned short u16;
typedef __attribute__((ext_vector_type(8))) short bf16x8;
typedef __attribute__((ext_vector_type(4))) float f32x4;
typedef __attribute__((ext_vector_type(16))) float f32x16;

// workspace layout (bf16 elements)
constexpr int OFF_W1 = 0;          // [3][128][128]  (l, h, c)
constexpr int OFF_W2 = 49152;      // [3][128][128]  (l, c, h)
constexpr int OFF_GW = 98304;      // [256][128]     (o, h)
constexpr int OFF_TG = 131072;     // [64][16]  rows>=42 / cols>=9 zero
constexpr int OFF_FG = 132096;     // [32][48]  rows>=9  / cols>=42 zero
constexpr int WS_ELEMS = 133632;   // bytes needed in d_ws = 267264

__device__ __forceinline__ u16 f2bf(float f) {
    unsigned u = __float_as_uint(f);
    u += 0x7FFFu + ((u >> 16) & 1u);   // RNE
    return (u16)(u >> 16);
}

__global__ void prep_kernel(const float* __restrict__ w1, const float* __restrict__ gw,
                            const float* __restrict__ w2, const float* __restrict__ tg,
                            const float* __restrict__ fg, u16* __restrict__ wsb) {
    const int idx = blockIdx.x * blockDim.x + threadIdx.x;
    const int str = gridDim.x * blockDim.x;
    for (int i = idx; i < 49152; i += str) wsb[OFF_W1 + i] = f2bf(w1[i]);
    for (int i = idx; i < 49152; i += str) wsb[OFF_W2 + i] = f2bf(w2[i]);
    for (int i = idx; i < 32768; i += str) wsb[OFF_GW + i] = f2bf(gw[i]);
    for (int i = idx; i < 1024; i += str) {
        int a = i >> 4, k = i & 15;
        wsb[OFF_TG + i] = (a < 42 && k < 9) ? f2bf(tg[a * 9 + k]) : (u16)0;
    }
    for (int i = idx; i < 1536; i += str) {
        int m = i / 48, k = i - m * 48;
        wsb[OFF_FG + i] = (m < 9 && k < 42) ? f2bf(fg[m * 42 + k]) : (u16)0;
    }
}

// 2 nodes per 256-thread WG.  LDS ~53.7 KB -> 3 WG/CU (160 KiB / 3 = 54613 B).
// batched-row layout (48 rows, degree-pure 16-row tiles):
//   l0: row = node (0..1); l1: row = 16 + node*3 + mm; l2: row = 32 + node*5 + mm
__global__ __launch_bounds__(256, 3) void eqffn_mfma(
    const float* __restrict__ x, const float* __restrict__ nw,
    const float* __restrict__ b1f, const float* __restrict__ gbf,
    const float* __restrict__ b2f, const u16* __restrict__ wsb,
    float* __restrict__ out, int N)
{
    __shared__ u16 sh_a1[48 * 136];   // A1 (packed norm acts), later h2b (union)   13056 B
    __shared__ u16 sh_h1T[2 * 128 * 20]; // both nodes: [nd][h][m-pad20]; cols 9..19 zero  10240 B
    __shared__ u16 sh_g[48 * 136];    // per-node grid acts [a][h]                  13056 B
    __shared__ u16 sh_g2T[128 * 52];  // per-node swiglu out [o][a-pad52]; cols 42..51 zero  13312 B
    __shared__ float sh_nw[384];
    __shared__ float sh_b1[128];
    __shared__ float sh_b2[128];
    __shared__ float sh_gb[256];
    __shared__ float sh_red[4];       // RMS partial sums (wave pairs)

    const int tid  = threadIdx.x;
    const int w    = tid >> 6;       // wave id
    const int lane = tid & 63;
    const int q    = lane >> 4;      // 16x16 quad
    const int r    = lane & 15;
    const int r32  = lane & 31;      // 32x32 row/col
    const int half = lane >> 5;
    const int n0   = blockIdx.x * 2;

    // ---- small hoisted weight fragments (L2-resident) ----
    const bf16x8 tgA0 = *(const bf16x8*)&wsb[OFF_TG + r32 * 16 + half * 8];
    const bf16x8 tgA1 = *(const bf16x8*)&wsb[OFF_TG + (32 + r32) * 16 + half * 8];
    bf16x8 fgA[3];
    #pragma unroll
    for (int k = 0; k < 3; ++k)
        fgA[k] = *(const bf16x8*)&wsb[OFF_FG + r32 * 48 + k * 16 + half * 8];

    // ---- init: stage small vectors, zero padded LDS regions ----
    for (int i = tid; i < 384; i += 256) sh_nw[i] = nw[i];
    if (tid < 128) { sh_b1[tid] = b1f[tid]; sh_b2[tid] = b2f[tid]; }
    sh_gb[tid] = gbf[tid];
    {
        unsigned long long* z1 = (unsigned long long*)sh_h1T;
        for (int i = tid; i < 1280; i += 256) z1[i] = 0ull;
        unsigned long long* z2 = (unsigned long long*)sh_g2T;
        for (int i = tid; i < 1664; i += 256) z2[i] = 0ull;
    }

    // ---- phase A: wave pair (2*nd, 2*nd+1) loads node n0+nd; half ph each ----
    const int nd0 = w >> 1;          // node this wave helps load (0..1)
    const int ph  = w & 1;           // which half of the 1152 floats
    const int myn = n0 + nd0;
    float4 xv[3];
    float ss = 0.f;
    if (myn < N) {
        const float4* xr = (const float4*)(x + (size_t)myn * 1152 + ph * 576);
        for (int i = lane, c2 = 0; i < 144; i += 64, ++c2) {
            float4 v = xr[i]; xv[c2] = v;
            ss += v.x * v.x + v.y * v.y + v.z * v.z + v.w * v.w;
        }
    }
    #pragma unroll
    for (int off = 32; off; off >>= 1) ss += __shfl_xor(ss, off);
    if (lane == 0) sh_red[w] = ss;
    __syncthreads();   // init + partial sums visible

    const float sstot = sh_red[2 * nd0] + sh_red[2 * nd0 + 1];
    const float inv = 1.0f / sqrtf(sstot * (1.0f / 1152.0f) + 1e-6f);
    if (myn < N) {
        for (int i = lane, c2 = 0; i < 144; i += 64, ++c2) {
            float4 v = xv[c2];
            #pragma unroll
            for (int e = 0; e < 4; ++e) {
                const int f = ph * 576 + i * 4 + e;
                const float val = ((const float*)&v)[e] * inv;
                int row, c, l;
                if (f < 128)      { l = 0; c = f;            row = nd0; }
                else if (f < 512) { int t = f - 128; l = 1; c = t / 3; row = 16 + nd0 * 3 + (t - c * 3); }
                else              { int t = f - 512; l = 2; c = t / 5; row = 32 + nd0 * 5 + (t - c * 5); }
                sh_a1[row * 136 + c] = f2bf(val * sh_nw[l * 128 + c]);
            }
        }
    }
    __syncthreads();   // A1 ready

    // ---- GEMM1 (3 degree-pure tiles, 16x16x32): h1[row][h] = sum_c A1[row][c] w1[l][h][c]
    // acc is transient (dies at the epilogue below) -> no cross-loop register pressure.
    {
        f32x4 acc1[3][2];
        #pragma unroll
        for (int a = 0; a < 3; ++a)
            #pragma unroll
            for (int b = 0; b < 2; ++b)
                #pragma unroll
                for (int e = 0; e < 4; ++e) acc1[a][b][e] = 0.f;
        #pragma unroll
        for (int mt = 0; mt < 3; ++mt) {           // l == mt
            #pragma unroll
            for (int k = 0; k < 4; ++k) {
                bf16x8 af = *(const bf16x8*)&sh_a1[(mt * 16 + r) * 136 + k * 32 + q * 8];
                #pragma unroll
                for (int nt = 0; nt < 2; ++nt) {
                    const int h = (2 * w + nt) * 16 + r;
                    bf16x8 bf = *(const bf16x8*)&wsb[OFF_W1 + (mt * 128 + h) * 128 + k * 32 + q * 8];
                    acc1[mt][nt] = __builtin_amdgcn_mfma_f32_16x16x32_bf16(af, bf, acc1[mt][nt], 0, 0, 0);
                }
            }
        }
        // epilogue: +b1 on l0, write both nodes' h1T slices (wave-local h columns)
        #pragma unroll
        for (int mt = 0; mt < 3; ++mt) {
            #pragma unroll
            for (int nt = 0; nt < 2; ++nt) {
                const int h = (2 * w + nt) * 16 + r;
                #pragma unroll
                for (int rg = 0; rg < 4; ++rg) {
                    const int rr = q * 4 + rg;
                    const float v = acc1[mt][nt][rg];
                    if (mt == 0) {
                        if (rr < 2) sh_h1T[rr * 2560 + h * 20 + 0] = f2bf(v + sh_b1[h]);
                    } else if (mt == 1) {
                        if (rr < 6) { int nd = rr / 3, mm = rr - nd * 3; sh_h1T[nd * 2560 + h * 20 + 1 + mm] = f2bf(v); }
                    } else {
                        if (rr < 10) { int nd = rr / 5, mm = rr - nd * 5; sh_h1T[nd * 2560 + h * 20 + 4 + mm] = f2bf(v); }
                    }
                }
            }
        }
    }
    // No barrier: h1T rows h in [32w,32w+32) are written and read by the same wave.

    // ---- per-node grid pipeline (2 iterations) ----
    for (int nn = 0; nn < 2; ++nn) {
        // to_grid (32x32x16): g[a][h] = sum_m tg[a][m] h1[nn][m][h]; wave w -> h block w*32
        {
            bf16x8 bfn = *(const bf16x8*)&sh_h1T[nn * 2560 + (w * 32 + r32) * 20 + half * 8];
            f32x16 ac0, ac1;
            #pragma unroll
            for (int e = 0; e < 16; ++e) { ac0[e] = 0.f; ac1[e] = 0.f; }
            ac0 = __builtin_amdgcn_mfma_f32_32x32x16_bf16(tgA0, bfn, ac0, 0, 0, 0);
            ac1 = __builtin_amdgcn_mfma_f32_32x32x16_bf16(tgA1, bfn, ac1, 0, 0, 0);
            const int h = w * 32 + r32;
            #pragma unroll
            for (int rg = 0; rg < 16; ++rg) {
                const int ar = (rg & 3) + 8 * (rg >> 2) + 4 * half;
                sh_g[ar * 136 + h] = f2bf(ac0[rg]);
                const int ar1 = 32 + ar;
                if (ar1 < 48) sh_g[ar1 * 136 + h] = f2bf(ac1[rg]);
            }
        }
        __syncthreads();   // g ready for all waves (also orders GEMM1 A-reads vs h2b writes)

        bf16x8 bfr[3][4];
        #pragma unroll
        for (int nt = 0; nt < 3; ++nt)
            #pragma unroll
            for (int k = 0; k < 4; ++k)
                bfr[nt][k] = *(const bf16x8*)&sh_g[(nt * 16 + r) * 136 + k * 32 + q * 8];
        __syncthreads();   // all g reads complete -> next iter may overwrite sh_g

        // SwiGLU (transposed, 16x16x32): zT[o][a] = sum_h gw[o][h] g[a][h]
        f32x4 aL[2][3], aH[2][3];
        #pragma unroll
        for (int p = 0; p < 2; ++p)
            #pragma unroll
            for (int nt = 0; nt < 3; ++nt)
                #pragma unroll
                for (int e = 0; e < 4; ++e) { aL[p][nt][e] = 0.f; aH[p][nt][e] = 0.f; }
        #pragma unroll
        for (int p = 0; p < 2; ++p) {
            const int oL = (2 * w + p) * 16 + r;
            #pragma unroll
            for (int k = 0; k < 4; ++k) {
                bf16x8 fL = *(const bf16x8*)&wsb[OFF_GW + oL * 128 + k * 32 + q * 8];
                bf16x8 fH = *(const bf16x8*)&wsb[OFF_GW + (oL + 128) * 128 + k * 32 + q * 8];
                #pragma unroll
                for (int nt = 0; nt < 3; ++nt) {
                    aL[p][nt] = __builtin_amdgcn_mfma_f32_16x16x32_bf16(fL, bfr[nt][k], aL[p][nt], 0, 0, 0);
                    aH[p][nt] = __builtin_amdgcn_mfma_f32_16x16x32_bf16(fH, bfr[nt][k], aH[p][nt], 0, 0, 0);
                }
            }
        }
        // silu epilogue -> g2T[o][a] (rows o = w*32..w*32+31: wave-local)
        #pragma unroll
        for (int p = 0; p < 2; ++p) {
            #pragma unroll
            for (int nt = 0; nt < 3; ++nt) {
                #pragma unroll
                for (int rg = 0; rg < 4; ++rg) {
                    const int o = (2 * w + p) * 16 + q * 4 + rg;
                    const int a = nt * 16 + r;
                    const float zl = aL[p][nt][rg] + sh_gb[o];
                    const float zh = aH[p][nt][rg] + sh_gb[128 + o];
                    const float gv = zl * (1.0f / (1.0f + __expf(-zl))) * zh;
                    if (a < 42) sh_g2T[o * 52 + a] = f2bf(gv);
                }
            }
        }

        // from_grid (32x32x16, K=48, wave-local rows of g2T): h2[m][h] = sum_a fg[m][a] g2T[h][a]
        {
            f32x16 ac;
            #pragma unroll
            for (int e = 0; e < 16; ++e) ac[e] = 0.f;
            const int h = w * 32 + r32;
            #pragma unroll
            for (int k = 0; k < 3; ++k) {
                bf16x8 bv = *(const bf16x8*)&sh_g2T[h * 52 + k * 16 + half * 8];
                ac = __builtin_amdgcn_mfma_f32_32x32x16_bf16(fgA[k], bv, ac, 0, 0, 0);
            }
            #pragma unroll
            for (int rg = 0; rg < 16; ++rg) {
                const int m = (rg & 3) + 8 * (rg >> 2) + 4 * half;
                if (m < 9) {
                    const int row = (m == 0) ? nn : ((m < 4) ? (16 + nn * 3 + (m - 1)) : (32 + nn * 5 + (m - 4)));
                    sh_a1[row * 136 + h] = f2bf(ac[rg]);
                }
            }
        }
    }
    __syncthreads();

    // ---- GEMM2 (3 degree-pure tiles, 16x16x32) + bias + unpack scatter store ----
    {
        f32x4 acc[3][2];
        #pragma unroll
        for (int a = 0; a < 3; ++a)
            #pragma unroll
            for (int b = 0; b < 2; ++b)
                #pragma unroll
                for (int e = 0; e < 4; ++e) acc[a][b][e] = 0.f;
        #pragma unroll
        for (int mt = 0; mt < 3; ++mt) {           // l == mt
            #pragma unroll
            for (int k = 0; k < 4; ++k) {
                bf16x8 af = *(const bf16x8*)&sh_a1[(mt * 16 + r) * 136 + k * 32 + q * 8];
                #pragma unroll
                for (int nt = 0; nt < 2; ++nt) {
                    const int c = (2 * w + nt) * 16 + r;
                    bf16x8 bf = *(const bf16x8*)&wsb[OFF_W2 + (mt * 128 + c) * 128 + k * 32 + q * 8];
                    acc[mt][nt] = __builtin_amdgcn_mfma_f32_16x16x32_bf16(af, bf, acc[mt][nt], 0, 0, 0);
                }
            }
        }
        #pragma unroll
        for (int mt = 0; mt < 3; ++mt) {
            #pragma unroll
            for (int nt = 0; nt < 2; ++nt) {
                const int c = (2 * w + nt) * 16 + r;
                #pragma unroll
                for (int rg = 0; rg < 4; ++rg) {
                    const int rr = q * 4 + rg;
                    const float v = acc[mt][nt][rg];
                    if (mt == 0) {
                        if (rr < 2) { int gn = n0 + rr; if (gn < N) out[(size_t)gn * 1152 + c] = v + sh_b2[c]; }
                    } else if (mt == 1) {
                        if (rr < 6) { int nd = rr / 3, mm = rr - nd * 3; int gn = n0 + nd;
                                      if (gn < N) out[(size_t)gn * 1152 + 128 + c * 3 + mm] = v; }
                    } else {
                        if (rr < 10) { int nd = rr / 5, mm = rr - nd * 5; int gn = n0 + nd;
                                       if (gn < N) out[(size_t)gn * 1152 + 512 + c * 5 + mm] = v; }
                    }
                }
            }
        }
    }
}

extern "C" void kernel_launch(void* const* d_in, const int* in_sizes, int n_in,
                              void* d_out, int out_size, void* d_ws, size_t ws_size,
                              hipStream_t stream)
{
    const float* x  = (const float*)d_in[0];
    const float* nw = (const float*)d_in[1];
    const float* w1 = (const float*)d_in[2];
    const float* b1 = (const float*)d_in[3];
    const float* gw = (const float*)d_in[4];
    const float* gb = (const float*)d_in[5];
    const float* w2 = (const float*)d_in[6];
    const float* b2 = (const float*)d_in[7];
    const float* tg = (const float*)d_in[8];
    const float* fg = (const float*)d_in[9];
    float* out = (float*)d_out;
    u16* wsb = (u16*)d_ws;

    const int N = in_sizes[0] / 1152;
    prep_kernel<<<64, 256, 0, stream>>>(w1, gw, w2, tg, fg, wsb);
    eqffn_mfma<<<(N + 1) / 2, 256, 0, stream>>>(x, nw, b1, gb, b2, wsb, out, N);
}

// Round 4
// 333.019 us; speedup vs baseline: 1.1539x; 1.0454x over previous
//
#include <hip/hip_runtime.h>
#include <math.h>

typedef unsigned short u16;
typedef __attribute__((ext_vector_type(8))) short bf16x8;
typedef __attribute__((ext_vector_type(4))) float f32x4;
typedef __attribute__((ext_vector_type(16))) float f32x16;

// workspace layout (bf16 elements)
constexpr int OFF_W1 = 0;          // [3][128][128]  (l, h, c)
constexpr int OFF_W2 = 49152;      // [3][128][128]  (l, c, h)
constexpr int OFF_GW = 98304;      // [256][128]     (o, h)
constexpr int OFF_TG = 131072;     // [64][16]  rows>=42 / cols>=9 zero
constexpr int OFF_FG = 132096;     // [32][48]  rows>=9  / cols>=42 zero
constexpr int WS_ELEMS = 133632;   // bytes needed in d_ws = 267264

__device__ __forceinline__ u16 f2bf(float f) {
    unsigned u = __float_as_uint(f);
    u += 0x7FFFu + ((u >> 16) & 1u);   // RNE
    return (u16)(u >> 16);
}

__global__ void prep_kernel(const float* __restrict__ w1, const float* __restrict__ gw,
                            const float* __restrict__ w2, const float* __restrict__ tg,
                            const float* __restrict__ fg, u16* __restrict__ wsb) {
    const int idx = blockIdx.x * blockDim.x + threadIdx.x;
    const int str = gridDim.x * blockDim.x;
    for (int i = idx; i < 49152; i += str) wsb[OFF_W1 + i] = f2bf(w1[i]);
    for (int i = idx; i < 49152; i += str) wsb[OFF_W2 + i] = f2bf(w2[i]);
    for (int i = idx; i < 32768; i += str) wsb[OFF_GW + i] = f2bf(gw[i]);
    for (int i = idx; i < 1024; i += str) {
        int a = i >> 4, k = i & 15;
        wsb[OFF_TG + i] = (a < 42 && k < 9) ? f2bf(tg[a * 9 + k]) : (u16)0;
    }
    for (int i = idx; i < 1536; i += str) {
        int m = i / 48, k = i - m * 48;
        wsb[OFF_FG + i] = (m < 9 && k < 42) ? f2bf(fg[m * 42 + k]) : (u16)0;
    }
}

// 2 nodes per 256-thread WG.  LDS ~53.7 KB -> 3 WG/CU (160 KiB / 3 = 54613 B)
// PROVIDED total regs (arch+acc) <= ~170.  launch_bounds(256,2): do NOT force a
// 3-wave register cap (rounds 2/3 showed (256,3) -> 84/84 split -> scratch spills).
// batched-row layout (48 rows, degree-pure 16-row tiles):
//   l0: row = node (0..1); l1: row = 16 + node*3 + mm; l2: row = 32 + node*5 + mm
__global__ __launch_bounds__(256, 2) void eqffn_mfma(
    const float* __restrict__ x, const float* __restrict__ nw,
    const float* __restrict__ b1f, const float* __restrict__ gbf,
    const float* __restrict__ b2f, const u16* __restrict__ wsb,
    float* __restrict__ out, int N)
{
    __shared__ u16 sh_a1[48 * 136];   // A1 (packed norm acts), later h2b (union)   13056 B
    __shared__ u16 sh_h1T[2 * 128 * 20]; // both nodes: [nd][h][m-pad20]; cols 9..19 zero  10240 B
    __shared__ u16 sh_g[48 * 136];    // per-node grid acts [a][h]                  13056 B
    __shared__ u16 sh_g2T[128 * 52];  // per-node swiglu out [o][a-pad52]; cols 42..51 zero  13312 B
    __shared__ float sh_nw[384];
    __shared__ float sh_b1[128];
    __shared__ float sh_b2[128];
    __shared__ float sh_gb[256];
    __shared__ float sh_red[4];       // RMS partial sums (wave pairs)

    const int tid  = threadIdx.x;
    const int w    = tid >> 6;       // wave id
    const int lane = tid & 63;
    const int q    = lane >> 4;      // 16x16 quad
    const int r    = lane & 15;
    const int r32  = lane & 31;      // 32x32 row/col
    const int half = lane >> 5;
    const int n0   = blockIdx.x * 2;

    // ---- small hoisted weight fragments (L2-resident) ----
    const bf16x8 tgA0 = *(const bf16x8*)&wsb[OFF_TG + r32 * 16 + half * 8];
    const bf16x8 tgA1 = *(const bf16x8*)&wsb[OFF_TG + (32 + r32) * 16 + half * 8];
    bf16x8 fgA[3];
    #pragma unroll
    for (int k = 0; k < 3; ++k)
        fgA[k] = *(const bf16x8*)&wsb[OFF_FG + r32 * 48 + k * 16 + half * 8];

    // ---- init: stage small vectors, zero padded LDS regions ----
    for (int i = tid; i < 384; i += 256) sh_nw[i] = nw[i];
    if (tid < 128) { sh_b1[tid] = b1f[tid]; sh_b2[tid] = b2f[tid]; }
    sh_gb[tid] = gbf[tid];
    {
        unsigned long long* z1 = (unsigned long long*)sh_h1T;
        for (int i = tid; i < 1280; i += 256) z1[i] = 0ull;
        unsigned long long* z2 = (unsigned long long*)sh_g2T;
        for (int i = tid; i < 1664; i += 256) z2[i] = 0ull;
    }

    // ---- phase A: wave pair (2*nd, 2*nd+1) loads node n0+nd; half ph each ----
    const int nd0 = w >> 1;          // node this wave helps load (0..1)
    const int ph  = w & 1;           // which half of the 1152 floats
    const int myn = n0 + nd0;
    float4 xv[3];
    float ss = 0.f;
    if (myn < N) {
        const float4* xr = (const float4*)(x + (size_t)myn * 1152 + ph * 576);
        for (int i = lane, c2 = 0; i < 144; i += 64, ++c2) {
            float4 v = xr[i]; xv[c2] = v;
            ss += v.x * v.x + v.y * v.y + v.z * v.z + v.w * v.w;
        }
    }
    #pragma unroll
    for (int off = 32; off; off >>= 1) ss += __shfl_xor(ss, off);
    if (lane == 0) sh_red[w] = ss;
    __syncthreads();   // init + partial sums visible

    const float sstot = sh_red[2 * nd0] + sh_red[2 * nd0 + 1];
    const float inv = 1.0f / sqrtf(sstot * (1.0f / 1152.0f) + 1e-6f);
    if (myn < N) {
        for (int i = lane, c2 = 0; i < 144; i += 64, ++c2) {
            float4 v = xv[c2];
            #pragma unroll
            for (int e = 0; e < 4; ++e) {
                const int f = ph * 576 + i * 4 + e;
                const float val = ((const float*)&v)[e] * inv;
                int row, c, l;
                if (f < 128)      { l = 0; c = f;            row = nd0; }
                else if (f < 512) { int t = f - 128; l = 1; c = t / 3; row = 16 + nd0 * 3 + (t - c * 3); }
                else              { int t = f - 512; l = 2; c = t / 5; row = 32 + nd0 * 5 + (t - c * 5); }
                sh_a1[row * 136 + c] = f2bf(val * sh_nw[l * 128 + c]);
            }
        }
    }
    __syncthreads();   // A1 ready

    // ---- GEMM1 (3 degree-pure tiles, 16x16x32): h1[row][h] = sum_c A1[row][c] w1[l][h][c]
    {
        f32x4 acc1[3][2];
        #pragma unroll
        for (int a = 0; a < 3; ++a)
            #pragma unroll
            for (int b = 0; b < 2; ++b)
                #pragma unroll
                for (int e = 0; e < 4; ++e) acc1[a][b][e] = 0.f;
        #pragma unroll
        for (int mt = 0; mt < 3; ++mt) {           // l == mt
            #pragma unroll
            for (int k = 0; k < 4; ++k) {
                bf16x8 af = *(const bf16x8*)&sh_a1[(mt * 16 + r) * 136 + k * 32 + q * 8];
                #pragma unroll
                for (int nt = 0; nt < 2; ++nt) {
                    const int h = (2 * w + nt) * 16 + r;
                    bf16x8 bf = *(const bf16x8*)&wsb[OFF_W1 + (mt * 128 + h) * 128 + k * 32 + q * 8];
                    acc1[mt][nt] = __builtin_amdgcn_mfma_f32_16x16x32_bf16(af, bf, acc1[mt][nt], 0, 0, 0);
                }
            }
        }
        // epilogue: +b1 on l0, write both nodes' h1T slices (wave-local h columns)
        #pragma unroll
        for (int mt = 0; mt < 3; ++mt) {
            #pragma unroll
            for (int nt = 0; nt < 2; ++nt) {
                const int h = (2 * w + nt) * 16 + r;
                #pragma unroll
                for (int rg = 0; rg < 4; ++rg) {
                    const int rr = q * 4 + rg;
                    const float v = acc1[mt][nt][rg];
                    if (mt == 0) {
                        if (rr < 2) sh_h1T[rr * 2560 + h * 20 + 0] = f2bf(v + sh_b1[h]);
                    } else if (mt == 1) {
                        if (rr < 6) { int nd = rr / 3, mm = rr - nd * 3; sh_h1T[nd * 2560 + h * 20 + 1 + mm] = f2bf(v); }
                    } else {
                        if (rr < 10) { int nd = rr / 5, mm = rr - nd * 5; sh_h1T[nd * 2560 + h * 20 + 4 + mm] = f2bf(v); }
                    }
                }
            }
        }
    }
    // No barrier: h1T rows h in [32w,32w+32) are written and read by the same wave.

    // ---- per-node grid pipeline (2 iterations) ----
    for (int nn = 0; nn < 2; ++nn) {
        // to_grid (32x32x16): g[a][h] = sum_m tg[a][m] h1[nn][m][h]; wave w -> h block w*32
        {
            bf16x8 bfn = *(const bf16x8*)&sh_h1T[nn * 2560 + (w * 32 + r32) * 20 + half * 8];
            f32x16 ac0, ac1;
            #pragma unroll
            for (int e = 0; e < 16; ++e) { ac0[e] = 0.f; ac1[e] = 0.f; }
            ac0 = __builtin_amdgcn_mfma_f32_32x32x16_bf16(tgA0, bfn, ac0, 0, 0, 0);
            ac1 = __builtin_amdgcn_mfma_f32_32x32x16_bf16(tgA1, bfn, ac1, 0, 0, 0);
            const int h = w * 32 + r32;
            #pragma unroll
            for (int rg = 0; rg < 16; ++rg) {
                const int ar = (rg & 3) + 8 * (rg >> 2) + 4 * half;
                sh_g[ar * 136 + h] = f2bf(ac0[rg]);
                const int ar1 = 32 + ar;
                if (ar1 < 48) sh_g[ar1 * 136 + h] = f2bf(ac1[rg]);
            }
        }
        __syncthreads();   // g ready for all waves (also orders GEMM1 A-reads vs h2b writes)

        // SwiGLU (transposed, 16x16x32): zT[o][a] = sum_h gw[o][h] g[a][h]
        // k-outer: only 3 B-fragments (12 VGPR) live per k-step -> low register peak.
        f32x4 aL[2][3], aH[2][3];
        #pragma unroll
        for (int p = 0; p < 2; ++p)
            #pragma unroll
            for (int nt = 0; nt < 3; ++nt)
                #pragma unroll
                for (int e = 0; e < 4; ++e) { aL[p][nt][e] = 0.f; aH[p][nt][e] = 0.f; }
        #pragma unroll
        for (int k = 0; k < 4; ++k) {
            bf16x8 bk[3];
            #pragma unroll
            for (int nt = 0; nt < 3; ++nt)
                bk[nt] = *(const bf16x8*)&sh_g[(nt * 16 + r) * 136 + k * 32 + q * 8];
            #pragma unroll
            for (int p = 0; p < 2; ++p) {
                const int oL = (2 * w + p) * 16 + r;
                bf16x8 fL = *(const bf16x8*)&wsb[OFF_GW + oL * 128 + k * 32 + q * 8];
                bf16x8 fH = *(const bf16x8*)&wsb[OFF_GW + (oL + 128) * 128 + k * 32 + q * 8];
                #pragma unroll
                for (int nt = 0; nt < 3; ++nt) {
                    aL[p][nt] = __builtin_amdgcn_mfma_f32_16x16x32_bf16(fL, bk[nt], aL[p][nt], 0, 0, 0);
                    aH[p][nt] = __builtin_amdgcn_mfma_f32_16x16x32_bf16(fH, bk[nt], aH[p][nt], 0, 0, 0);
                }
            }
        }
        __syncthreads();   // all g reads complete -> next iter may overwrite sh_g

        // silu epilogue -> g2T[o][a] (rows o = w*32..w*32+31: wave-local)
        #pragma unroll
        for (int p = 0; p < 2; ++p) {
            #pragma unroll
            for (int nt = 0; nt < 3; ++nt) {
                #pragma unroll
                for (int rg = 0; rg < 4; ++rg) {
                    const int o = (2 * w + p) * 16 + q * 4 + rg;
                    const int a = nt * 16 + r;
                    const float zl = aL[p][nt][rg] + sh_gb[o];
                    const float zh = aH[p][nt][rg] + sh_gb[128 + o];
                    const float gv = zl * (1.0f / (1.0f + __expf(-zl))) * zh;
                    if (a < 42) sh_g2T[o * 52 + a] = f2bf(gv);
                }
            }
        }

        // from_grid (32x32x16, K=48, wave-local rows of g2T): h2[m][h] = sum_a fg[m][a] g2T[h][a]
        {
            f32x16 ac;
            #pragma unroll
            for (int e = 0; e < 16; ++e) ac[e] = 0.f;
            const int h = w * 32 + r32;
            #pragma unroll
            for (int k = 0; k < 3; ++k) {
                bf16x8 bv = *(const bf16x8*)&sh_g2T[h * 52 + k * 16 + half * 8];
                ac = __builtin_amdgcn_mfma_f32_32x32x16_bf16(fgA[k], bv, ac, 0, 0, 0);
            }
            #pragma unroll
            for (int rg = 0; rg < 16; ++rg) {
                const int m = (rg & 3) + 8 * (rg >> 2) + 4 * half;
                if (m < 9) {
                    const int row = (m == 0) ? nn : ((m < 4) ? (16 + nn * 3 + (m - 1)) : (32 + nn * 5 + (m - 4)));
                    sh_a1[row * 136 + h] = f2bf(ac[rg]);
                }
            }
        }
    }
    __syncthreads();

    // ---- GEMM2 (3 degree-pure tiles, 16x16x32) + bias + unpack scatter store ----
    {
        f32x4 acc[3][2];
        #pragma unroll
        for (int a = 0; a < 3; ++a)
            #pragma unroll
            for (int b = 0; b < 2; ++b)
                #pragma unroll
                for (int e = 0; e < 4; ++e) acc[a][b][e] = 0.f;
        #pragma unroll
        for (int mt = 0; mt < 3; ++mt) {           // l == mt
            #pragma unroll
            for (int k = 0; k < 4; ++k) {
                bf16x8 af = *(const bf16x8*)&sh_a1[(mt * 16 + r) * 136 + k * 32 + q * 8];
                #pragma unroll
                for (int nt = 0; nt < 2; ++nt) {
                    const int c = (2 * w + nt) * 16 + r;
                    bf16x8 bf = *(const bf16x8*)&wsb[OFF_W2 + (mt * 128 + c) * 128 + k * 32 + q * 8];
                    acc[mt][nt] = __builtin_amdgcn_mfma_f32_16x16x32_bf16(af, bf, acc[mt][nt], 0, 0, 0);
                }
            }
        }
        #pragma unroll
        for (int mt = 0; mt < 3; ++mt) {
            #pragma unroll
            for (int nt = 0; nt < 2; ++nt) {
                const int c = (2 * w + nt) * 16 + r;
                #pragma unroll
                for (int rg = 0; rg < 4; ++rg) {
                    const int rr = q * 4 + rg;
                    const float v = acc[mt][nt][rg];
                    if (mt == 0) {
                        if (rr < 2) { int gn = n0 + rr; if (gn < N) out[(size_t)gn * 1152 + c] = v + sh_b2[c]; }
                    } else if (mt == 1) {
                        if (rr < 6) { int nd = rr / 3, mm = rr - nd * 3; int gn = n0 + nd;
                                      if (gn < N) out[(size_t)gn * 1152 + 128 + c * 3 + mm] = v; }
                    } else {
                        if (rr < 10) { int nd = rr / 5, mm = rr - nd * 5; int gn = n0 + nd;
                                       if (gn < N) out[(size_t)gn * 1152 + 512 + c * 5 + mm] = v; }
                    }
                }
            }
        }
    }
}

extern "C" void kernel_launch(void* const* d_in, const int* in_sizes, int n_in,
                              void* d_out, int out_size, void* d_ws, size_t ws_size,
                              hipStream_t stream)
{
    const float* x  = (const float*)d_in[0];
    const float* nw = (const float*)d_in[1];
    const float* w1 = (const float*)d_in[2];
    const float* b1 = (const float*)d_in[3];
    const float* gw = (const float*)d_in[4];
    const float* gb = (const float*)d_in[5];
    const float* w2 = (const float*)d_in[6];
    const float* b2 = (const float*)d_in[7];
    const float* tg = (const float*)d_in[8];
    const float* fg = (const float*)d_in[9];
    float* out = (float*)d_out;
    u16* wsb = (u16*)d_ws;

    const int N = in_sizes[0] / 1152;
    prep_kernel<<<64, 256, 0, stream>>>(w1, gw, w2, tg, fg, wsb);
    eqffn_mfma<<<(N + 1) / 2, 256, 0, stream>>>(x, nw, b1, gb, b2, wsb, out, N);
}

// Round 5
// 257.464 us; speedup vs baseline: 1.4926x; 1.2935x over previous
//
#include <hip/hip_runtime.h>
#include <math.h>

typedef unsigned short u16;
typedef __attribute__((ext_vector_type(8))) short bf16x8;
typedef __attribute__((ext_vector_type(4))) float f32x4;
typedef __attribute__((ext_vector_type(16))) float f32x16;

// workspace layout (bf16 elements)
constexpr int OFF_W1 = 0;          // [3][128][128]  (l, h, c)
constexpr int OFF_W2 = 49152;      // [3][128][128]  (l, c, h)
constexpr int OFF_GW = 98304;      // [256][128]     (o, h)
constexpr int OFF_TG = 131072;     // [64][16]  rows>=42 / cols>=9 zero
constexpr int OFF_FG = 132096;     // [32][48]  rows>=9  / cols>=42 zero
constexpr int WS_ELEMS = 133632;   // bytes needed in d_ws = 267264

__device__ __forceinline__ u16 f2bf(float f) {
    unsigned u = __float_as_uint(f);
    u += 0x7FFFu + ((u >> 16) & 1u);   // RNE
    return (u16)(u >> 16);
}

__global__ void prep_kernel(const float* __restrict__ w1, const float* __restrict__ gw,
                            const float* __restrict__ w2, const float* __restrict__ tg,
                            const float* __restrict__ fg, u16* __restrict__ wsb) {
    const int idx = blockIdx.x * blockDim.x + threadIdx.x;
    const int str = gridDim.x * blockDim.x;
    for (int i = idx; i < 49152; i += str) wsb[OFF_W1 + i] = f2bf(w1[i]);
    for (int i = idx; i < 49152; i += str) wsb[OFF_W2 + i] = f2bf(w2[i]);
    for (int i = idx; i < 32768; i += str) wsb[OFF_GW + i] = f2bf(gw[i]);
    for (int i = idx; i < 1024; i += str) {
        int a = i >> 4, k = i & 15;
        wsb[OFF_TG + i] = (a < 42 && k < 9) ? f2bf(tg[a * 9 + k]) : (u16)0;
    }
    for (int i = idx; i < 1536; i += str) {
        int m = i / 48, k = i - m * 48;
        wsb[OFF_FG + i] = (m < 9 && k < 42) ? f2bf(fg[m * 42 + k]) : (u16)0;
    }
}

// 4 nodes per 256-thread WG (round-0 structure), grid loop processes node PAIRS.
// LDS 80896 B -> 2 WG/CU.  6 barriers/WG (was 12).
// batched-row layout (64 rows): l0: rows 0..3 (node), l1: 16+n*3+mm, l2: 32+n*5+mm
__global__ __launch_bounds__(256, 2) void eqffn_mfma(
    const float* __restrict__ x, const float* __restrict__ nw,
    const float* __restrict__ b1f, const float* __restrict__ gbf,
    const float* __restrict__ b2f, const u16* __restrict__ wsb,
    float* __restrict__ out, int N)
{
    __shared__ u16 sh_a1[64 * 136];      // A1 (packed norm acts), later h2b (union) 17408 B
    __shared__ u16 sh_h1T[4 * 128 * 20]; // per node: [h][m-pad20]; cols 9..19 zero  20480 B
    __shared__ u16 sh_g[2][48 * 136];    // node-pair grid acts [a][h]               26112 B
    __shared__ u16 sh_g2T[128 * 52];     // swiglu out [o][a-pad52]; cols 42..51 zero 13312 B
    __shared__ float sh_nw[384];
    __shared__ float sh_b1[128];
    __shared__ float sh_b2[128];
    __shared__ float sh_gb[256];

    const int tid  = threadIdx.x;
    const int w    = tid >> 6;       // wave id
    const int lane = tid & 63;
    const int q    = lane >> 4;      // 16x16 quad
    const int r    = lane & 15;
    const int r32  = lane & 31;      // 32x32 row/col
    const int half = lane >> 5;
    const int n0   = blockIdx.x * 4;

    // ---- small hoisted weight fragments (L2-resident, 5 frags = 20 VGPR) ----
    const bf16x8 tgA0 = *(const bf16x8*)&wsb[OFF_TG + r32 * 16 + half * 8];
    const bf16x8 tgA1 = *(const bf16x8*)&wsb[OFF_TG + (32 + r32) * 16 + half * 8];
    bf16x8 fgA[3];
    #pragma unroll
    for (int k = 0; k < 3; ++k)
        fgA[k] = *(const bf16x8*)&wsb[OFF_FG + r32 * 48 + k * 16 + half * 8];

    // ---- init: stage small vectors, zero padded LDS regions ----
    for (int i = tid; i < 384; i += 256) sh_nw[i] = nw[i];
    if (tid < 128) { sh_b1[tid] = b1f[tid]; sh_b2[tid] = b2f[tid]; }
    sh_gb[tid] = gbf[tid];
    {
        unsigned long long* z1 = (unsigned long long*)sh_h1T;
        for (int i = tid; i < 2560; i += 256) z1[i] = 0ull;
        unsigned long long* z2 = (unsigned long long*)sh_g2T;
        for (int i = tid; i < 1664; i += 256) z2[i] = 0ull;
    }
    __syncthreads();

    // ---- phase A: load x (wave w -> node n0+w), RMS, pack+normalize -> A1 bf16 ----
    const int myn = n0 + w;
    float4 xv[5];
    float ss = 0.f;
    if (myn < N) {
        const float4* xr = (const float4*)(x + (size_t)myn * 1152);
        for (int i = lane, c2 = 0; i < 288; i += 64, ++c2) {
            float4 v = xr[i]; xv[c2] = v;
            ss += v.x * v.x + v.y * v.y + v.z * v.z + v.w * v.w;
        }
    }
    #pragma unroll
    for (int off = 32; off; off >>= 1) ss += __shfl_xor(ss, off);
    const float inv = 1.0f / sqrtf(ss * (1.0f / 1152.0f) + 1e-6f);
    if (myn < N) {
        for (int i = lane, c2 = 0; i < 288; i += 64, ++c2) {
            float4 v = xv[c2];
            #pragma unroll
            for (int e = 0; e < 4; ++e) {
                const int f = i * 4 + e;
                const float val = ((const float*)&v)[e] * inv;
                int row, c, l;
                if (f < 128)      { l = 0; c = f;            row = w; }
                else if (f < 512) { int t = f - 128; l = 1; c = t / 3; row = 16 + w * 3 + (t - c * 3); }
                else              { int t = f - 512; l = 2; c = t / 5; row = 32 + w * 5 + (t - c * 5); }
                sh_a1[row * 136 + c] = f2bf(val * sh_nw[l * 128 + c]);
            }
        }
    }
    __syncthreads();   // A1 ready

    // ---- GEMM1 (batched, 16x16x32): h1[row][h] = sum_c A1[row][c] w1[l][h][c] ----
    {
        f32x4 acc[4][2];
        #pragma unroll
        for (int a = 0; a < 4; ++a)
            #pragma unroll
            for (int b = 0; b < 2; ++b)
                #pragma unroll
                for (int e = 0; e < 4; ++e) acc[a][b][e] = 0.f;
        #pragma unroll
        for (int mt = 0; mt < 4; ++mt) {
            const int l = (mt == 0) ? 0 : ((mt == 1) ? 1 : 2);
            #pragma unroll
            for (int k = 0; k < 4; ++k) {
                bf16x8 af = *(const bf16x8*)&sh_a1[(mt * 16 + r) * 136 + k * 32 + q * 8];
                #pragma unroll
                for (int nt = 0; nt < 2; ++nt) {
                    const int h = (2 * w + nt) * 16 + r;
                    bf16x8 bf = *(const bf16x8*)&wsb[OFF_W1 + (l * 128 + h) * 128 + k * 32 + q * 8];
                    acc[mt][nt] = __builtin_amdgcn_mfma_f32_16x16x32_bf16(af, bf, acc[mt][nt], 0, 0, 0);
                }
            }
        }
        // epilogue: +b1 on l0, write h1T[node][h][m] (stride 20 u16 = 10 banks -> 2-way, free)
        #pragma unroll
        for (int mt = 0; mt < 4; ++mt) {
            #pragma unroll
            for (int nt = 0; nt < 2; ++nt) {
                const int h = (2 * w + nt) * 16 + r;
                #pragma unroll
                for (int rg = 0; rg < 4; ++rg) {
                    const int rr = q * 4 + rg;
                    const float v = acc[mt][nt][rg];
                    if (mt == 0) {
                        if (rr < 4) sh_h1T[(rr * 128 + h) * 20 + 0] = f2bf(v + sh_b1[h]);
                    } else if (mt == 1) {
                        if (rr < 12) { int nd = rr / 3, mm = rr - nd * 3; sh_h1T[(nd * 128 + h) * 20 + 1 + mm] = f2bf(v); }
                    } else {
                        int rr2 = (mt - 2) * 16 + rr;
                        if (rr2 < 20) { int nd = rr2 / 5, mm = rr2 - nd * 5; sh_h1T[(nd * 128 + h) * 20 + 4 + mm] = f2bf(v); }
                    }
                }
            }
        }
    }
    // No barrier: h1T rows h in [32w,32w+32) are wave-local (written+read by wave w).

    // ---- grid pipeline over node PAIRS (2 iterations, 2 nodes in flight each) ----
    for (int it = 0; it < 2; ++it) {
        // to_grid both nodes of the pair -> sh_g[0], sh_g[1]
        #pragma unroll
        for (int j = 0; j < 2; ++j) {
            const int nn = 2 * it + j;
            bf16x8 bfn = *(const bf16x8*)&sh_h1T[(nn * 128 + w * 32 + r32) * 20 + half * 8];
            f32x16 ac0, ac1;
            #pragma unroll
            for (int e = 0; e < 16; ++e) { ac0[e] = 0.f; ac1[e] = 0.f; }
            ac0 = __builtin_amdgcn_mfma_f32_32x32x16_bf16(tgA0, bfn, ac0, 0, 0, 0);
            ac1 = __builtin_amdgcn_mfma_f32_32x32x16_bf16(tgA1, bfn, ac1, 0, 0, 0);
            const int h = w * 32 + r32;
            #pragma unroll
            for (int rg = 0; rg < 16; ++rg) {
                const int ar = (rg & 3) + 8 * (rg >> 2) + 4 * half;
                sh_g[j][ar * 136 + h] = f2bf(ac0[rg]);
                const int ar1 = 32 + ar;
                if (ar1 < 48) sh_g[j][ar1 * 136 + h] = f2bf(ac1[rg]);
            }
        }
        __syncthreads();   // g[0],g[1] ready (it=0: also orders GEMM1 a1-reads vs h2b writes)

        // SwiGLU both nodes (16x16x32): zT[o][a] = sum_h gw[o][h] g[a][h]
        // each GW fragment feeds both nodes -> global loads halved, MFMA ILP doubled.
        f32x4 sL[2][2][3], sH[2][2][3];
        #pragma unroll
        for (int j = 0; j < 2; ++j)
            #pragma unroll
            for (int p = 0; p < 2; ++p)
                #pragma unroll
                for (int nt = 0; nt < 3; ++nt)
                    #pragma unroll
                    for (int e = 0; e < 4; ++e) { sL[j][p][nt][e] = 0.f; sH[j][p][nt][e] = 0.f; }
        #pragma unroll
        for (int k = 0; k < 4; ++k) {
            bf16x8 bk[2][3];
            #pragma unroll
            for (int j = 0; j < 2; ++j)
                #pragma unroll
                for (int nt = 0; nt < 3; ++nt)
                    bk[j][nt] = *(const bf16x8*)&sh_g[j][(nt * 16 + r) * 136 + k * 32 + q * 8];
            #pragma unroll
            for (int p = 0; p < 2; ++p) {
                const int oL = (2 * w + p) * 16 + r;
                bf16x8 fL = *(const bf16x8*)&wsb[OFF_GW + oL * 128 + k * 32 + q * 8];
                bf16x8 fH = *(const bf16x8*)&wsb[OFF_GW + (oL + 128) * 128 + k * 32 + q * 8];
                #pragma unroll
                for (int j = 0; j < 2; ++j) {
                    #pragma unroll
                    for (int nt = 0; nt < 3; ++nt) {
                        sL[j][p][nt] = __builtin_amdgcn_mfma_f32_16x16x32_bf16(fL, bk[j][nt], sL[j][p][nt], 0, 0, 0);
                        sH[j][p][nt] = __builtin_amdgcn_mfma_f32_16x16x32_bf16(fH, bk[j][nt], sH[j][p][nt], 0, 0, 0);
                    }
                }
            }
        }
        if (it == 0) __syncthreads();  // all g reads complete -> next iter may overwrite sh_g
                                       // (last iter: no reuse, skip the barrier)

        // per node of the pair: silu -> g2T (wave-local rows) -> from_grid -> h2b
        #pragma unroll
        for (int j = 0; j < 2; ++j) {
            const int nn = 2 * it + j;
            #pragma unroll
            for (int p = 0; p < 2; ++p) {
                #pragma unroll
                for (int nt = 0; nt < 3; ++nt) {
                    #pragma unroll
                    for (int rg = 0; rg < 4; ++rg) {
                        const int o = (2 * w + p) * 16 + q * 4 + rg;
                        const int a = nt * 16 + r;
                        const float zl = sL[j][p][nt][rg] + sh_gb[o];
                        const float zh = sH[j][p][nt][rg] + sh_gb[128 + o];
                        const float gv = zl * (1.0f / (1.0f + __expf(-zl))) * zh;
                        if (a < 42) sh_g2T[o * 52 + a] = f2bf(gv);
                    }
                }
            }
            // from_grid (32x32x16, K=48, wave-local rows of g2T)
            {
                f32x16 ac;
                #pragma unroll
                for (int e = 0; e < 16; ++e) ac[e] = 0.f;
                const int h = w * 32 + r32;
                #pragma unroll
                for (int k = 0; k < 3; ++k) {
                    bf16x8 bv = *(const bf16x8*)&sh_g2T[h * 52 + k * 16 + half * 8];
                    ac = __builtin_amdgcn_mfma_f32_32x32x16_bf16(fgA[k], bv, ac, 0, 0, 0);
                }
                #pragma unroll
                for (int rg = 0; rg < 16; ++rg) {
                    const int m = (rg & 3) + 8 * (rg >> 2) + 4 * half;
                    if (m < 9) {
                        const int row = (m == 0) ? nn : ((m < 4) ? (16 + nn * 3 + (m - 1)) : (32 + nn * 5 + (m - 4)));
                        sh_a1[row * 136 + h] = f2bf(ac[rg]);
                    }
                }
            }
        }
    }
    __syncthreads();

    // ---- GEMM2 (batched, 16x16x32) + bias + unpack scatter store ----
    {
        f32x4 acc[4][2];
        #pragma unroll
        for (int a = 0; a < 4; ++a)
            #pragma unroll
            for (int b = 0; b < 2; ++b)
                #pragma unroll
                for (int e = 0; e < 4; ++e) acc[a][b][e] = 0.f;
        #pragma unroll
        for (int mt = 0; mt < 4; ++mt) {
            const int l = (mt == 0) ? 0 : ((mt == 1) ? 1 : 2);
            #pragma unroll
            for (int k = 0; k < 4; ++k) {
                bf16x8 af = *(const bf16x8*)&sh_a1[(mt * 16 + r) * 136 + k * 32 + q * 8];
                #pragma unroll
                for (int nt = 0; nt < 2; ++nt) {
                    const int c = (2 * w + nt) * 16 + r;
                    bf16x8 bf = *(const bf16x8*)&wsb[OFF_W2 + (l * 128 + c) * 128 + k * 32 + q * 8];
                    acc[mt][nt] = __builtin_amdgcn_mfma_f32_16x16x32_bf16(af, bf, acc[mt][nt], 0, 0, 0);
                }
            }
        }
        #pragma unroll
        for (int mt = 0; mt < 4; ++mt) {
            #pragma unroll
            for (int nt = 0; nt < 2; ++nt) {
                const int c = (2 * w + nt) * 16 + r;
                #pragma unroll
                for (int rg = 0; rg < 4; ++rg) {
                    const int rr = q * 4 + rg;
                    const float v = acc[mt][nt][rg];
                    if (mt == 0) {
                        if (rr < 4) { int gn = n0 + rr; if (gn < N) out[(size_t)gn * 1152 + c] = v + sh_b2[c]; }
                    } else if (mt == 1) {
                        if (rr < 12) { int nd = rr / 3, mm = rr - nd * 3; int gn = n0 + nd;
                                       if (gn < N) out[(size_t)gn * 1152 + 128 + c * 3 + mm] = v; }
                    } else {
                        int rr2 = (mt - 2) * 16 + rr;
                        if (rr2 < 20) { int nd = rr2 / 5, mm = rr2 - nd * 5; int gn = n0 + nd;
                                        if (gn < N) out[(size_t)gn * 1152 + 512 + c * 5 + mm] = v; }
                    }
                }
            }
        }
    }
}

extern "C" void kernel_launch(void* const* d_in, const int* in_sizes, int n_in,
                              void* d_out, int out_size, void* d_ws, size_t ws_size,
                              hipStream_t stream)
{
    const float* x  = (const float*)d_in[0];
    const float* nw = (const float*)d_in[1];
    const float* w1 = (const float*)d_in[2];
    const float* b1 = (const float*)d_in[3];
    const float* gw = (const float*)d_in[4];
    const float* gb = (const float*)d_in[5];
    const float* w2 = (const float*)d_in[6];
    const float* b2 = (const float*)d_in[7];
    const float* tg = (const float*)d_in[8];
    const float* fg = (const float*)d_in[9];
    float* out = (float*)d_out;
    u16* wsb = (u16*)d_ws;

    const int N = in_sizes[0] / 1152;
    prep_kernel<<<64, 256, 0, stream>>>(w1, gw, w2, tg, fg, wsb);
    eqffn_mfma<<<(N + 3) / 4, 256, 0, stream>>>(x, nw, b1, gb, b2, wsb, out, N);
}

// Round 7
// 251.157 us; speedup vs baseline: 1.5300x; 1.0251x over previous
//
#include <hip/hip_runtime.h>
#include <math.h>

typedef unsigned short u16;
typedef __attribute__((ext_vector_type(8))) short bf16x8;
typedef __attribute__((ext_vector_type(4))) float f32x4;
typedef __attribute__((ext_vector_type(16))) float f32x16;

// workspace layout (bf16 elements)
constexpr int OFF_W1 = 0;          // [3][128][128]  (l, h, c)
constexpr int OFF_W2 = 49152;      // [3][128][128]  (l, c, h)
constexpr int OFF_GW = 98304;      // [256][128]     (o, h)
constexpr int OFF_TG = 131072;     // [64][16]  rows>=42 / cols>=9 zero
constexpr int OFF_FG = 132096;     // [32][48]  rows>=9  / cols>=42 zero
constexpr int WS_ELEMS = 133632;   // bytes needed in d_ws = 267264

// f32 -> bf16 RNE via native compiler cast (gfx950: lowers to v_cvt_pk_bf16_f32).
__device__ __forceinline__ u16 f2bf(float f) {
    union { __bf16 b; u16 u; } cv;
    cv.b = (__bf16)f;
    return cv.u;
}
// packed pair: lo = cvt(a), hi = cvt(b)
__device__ __forceinline__ unsigned f2bf2(float a, float b) {
    return (unsigned)f2bf(a) | ((unsigned)f2bf(b) << 16);
}

__global__ void prep_kernel(const float* __restrict__ w1, const float* __restrict__ gw,
                            const float* __restrict__ w2, const float* __restrict__ tg,
                            const float* __restrict__ fg, u16* __restrict__ wsb) {
    const int idx = blockIdx.x * blockDim.x + threadIdx.x;
    const int str = gridDim.x * blockDim.x;
    for (int i = idx; i < 49152; i += str) wsb[OFF_W1 + i] = f2bf(w1[i]);
    for (int i = idx; i < 49152; i += str) wsb[OFF_W2 + i] = f2bf(w2[i]);
    for (int i = idx; i < 32768; i += str) wsb[OFF_GW + i] = f2bf(gw[i]);
    for (int i = idx; i < 1024; i += str) {
        int a = i >> 4, k = i & 15;
        wsb[OFF_TG + i] = (a < 42 && k < 9) ? f2bf(tg[a * 9 + k]) : (u16)0;
    }
    for (int i = idx; i < 1536; i += str) {
        int m = i / 48, k = i - m * 48;
        wsb[OFF_FG + i] = (m < 9 && k < 42) ? f2bf(fg[m * 42 + k]) : (u16)0;
    }
}

// 4 nodes per 256-thread WG, grid loop processes node PAIRS.  LDS ~79 KB -> 2 WG/CU.
// batched-row layout (64 rows): l0: rows 0..3 (node), l1: 16+n*3+mm, l2: 32+n*5+mm
__global__ __launch_bounds__(256, 2) void eqffn_mfma(
    const float* __restrict__ x, const float* __restrict__ nw,
    const float* __restrict__ b1f, const float* __restrict__ gbf,
    const float* __restrict__ b2f, const u16* __restrict__ wsb,
    float* __restrict__ out, int N)
{
    __shared__ __align__(16) u16 sh_a1[64 * 136];      // A1 (packed norm acts), later h2b 17408 B
    __shared__ __align__(16) u16 sh_h1T[4 * 128 * 20]; // per node: [h][m-pad20]; cols 9..19 zero 20480 B
    __shared__ __align__(16) u16 sh_g[2][48 * 136];    // node-pair grid acts [a][h]        26112 B
    __shared__ __align__(16) u16 sh_g2T[128 * 52];     // swiglu out [o][a-pad52]           13312 B
    __shared__ float sh_nw[384];
    __shared__ float sh_b1[128];
    __shared__ float sh_b2[128];
    __shared__ float sh_gb[256];

    const int tid  = threadIdx.x;
    const int w    = tid >> 6;       // wave id
    const int lane = tid & 63;
    const int q    = lane >> 4;      // 16x16 quad
    const int r    = lane & 15;
    const int r32  = lane & 31;      // 32x32 row/col
    const int half = lane >> 5;
    const int n0   = blockIdx.x * 4;

    // ---- small hoisted weight fragments (L2-resident, 5 frags = 20 VGPR) ----
    const bf16x8 tgA0 = *(const bf16x8*)&wsb[OFF_TG + r32 * 16 + half * 8];
    const bf16x8 tgA1 = *(const bf16x8*)&wsb[OFF_TG + (32 + r32) * 16 + half * 8];
    bf16x8 fgA[3];
    #pragma unroll
    for (int k = 0; k < 3; ++k)
        fgA[k] = *(const bf16x8*)&wsb[OFF_FG + r32 * 48 + k * 16 + half * 8];

    // ---- init: stage small vectors, zero padded LDS regions ----
    for (int i = tid; i < 384; i += 256) sh_nw[i] = nw[i];
    if (tid < 128) { sh_b1[tid] = b1f[tid]; sh_b2[tid] = b2f[tid]; }
    sh_gb[tid] = gbf[tid];
    {
        unsigned long long* z1 = (unsigned long long*)sh_h1T;
        for (int i = tid; i < 2560; i += 256) z1[i] = 0ull;
        unsigned long long* z2 = (unsigned long long*)sh_g2T;
        for (int i = tid; i < 1664; i += 256) z2[i] = 0ull;
    }
    __syncthreads();

    // ---- phase A: load x (wave w -> node n0+w), RMS, pack+normalize -> A1 bf16 ----
    const int myn = n0 + w;
    float4 xv[5];
    float ss = 0.f;
    if (myn < N) {
        const float4* xr = (const float4*)(x + (size_t)myn * 1152);
        for (int i = lane, c2 = 0; i < 288; i += 64, ++c2) {
            float4 v = xr[i]; xv[c2] = v;
            ss += v.x * v.x + v.y * v.y + v.z * v.z + v.w * v.w;
        }
    }
    #pragma unroll
    for (int off = 32; off; off >>= 1) ss += __shfl_xor(ss, off);
    const float inv = 1.0f / sqrtf(ss * (1.0f / 1152.0f) + 1e-6f);
    if (myn < N) {
        for (int i = lane, c2 = 0; i < 288; i += 64, ++c2) {
            float4 v = xv[c2];
            #pragma unroll
            for (int e = 0; e < 4; ++e) {
                const int f = i * 4 + e;
                const float val = ((const float*)&v)[e] * inv;
                int row, c, l;
                if (f < 128)      { l = 0; c = f;            row = w; }
                else if (f < 512) { int t = f - 128; l = 1; c = t / 3; row = 16 + w * 3 + (t - c * 3); }
                else              { int t = f - 512; l = 2; c = t / 5; row = 32 + w * 5 + (t - c * 5); }
                sh_a1[row * 136 + c] = f2bf(val * sh_nw[l * 128 + c]);
            }
        }
    }
    __syncthreads();   // A1 ready

    // ---- GEMM1 (batched, 16x16x32): h1[row][h] = sum_c A1[row][c] w1[l][h][c] ----
    {
        f32x4 acc[4][2];
        #pragma unroll
        for (int a = 0; a < 4; ++a)
            #pragma unroll
            for (int b = 0; b < 2; ++b)
                #pragma unroll
                for (int e = 0; e < 4; ++e) acc[a][b][e] = 0.f;
        #pragma unroll
        for (int mt = 0; mt < 4; ++mt) {
            const int l = (mt == 0) ? 0 : ((mt == 1) ? 1 : 2);
            #pragma unroll
            for (int k = 0; k < 4; ++k) {
                bf16x8 af = *(const bf16x8*)&sh_a1[(mt * 16 + r) * 136 + k * 32 + q * 8];
                #pragma unroll
                for (int nt = 0; nt < 2; ++nt) {
                    const int h = (2 * w + nt) * 16 + r;
                    bf16x8 bf = *(const bf16x8*)&wsb[OFF_W1 + (l * 128 + h) * 128 + k * 32 + q * 8];
                    acc[mt][nt] = __builtin_amdgcn_mfma_f32_16x16x32_bf16(af, bf, acc[mt][nt], 0, 0, 0);
                }
            }
        }
        // epilogue: +b1 on l0, write h1T[node][h][m] (stride 20 u16 = 10 banks -> 2-way, free)
        #pragma unroll
        for (int mt = 0; mt < 4; ++mt) {
            #pragma unroll
            for (int nt = 0; nt < 2; ++nt) {
                const int h = (2 * w + nt) * 16 + r;
                #pragma unroll
                for (int rg = 0; rg < 4; ++rg) {
                    const int rr = q * 4 + rg;
                    const float v = acc[mt][nt][rg];
                    if (mt == 0) {
                        if (rr < 4) sh_h1T[(rr * 128 + h) * 20 + 0] = f2bf(v + sh_b1[h]);
                    } else if (mt == 1) {
                        if (rr < 12) { int nd = rr / 3, mm = rr - nd * 3; sh_h1T[(nd * 128 + h) * 20 + 1 + mm] = f2bf(v); }
                    } else {
                        int rr2 = (mt - 2) * 16 + rr;
                        if (rr2 < 20) { int nd = rr2 / 5, mm = rr2 - nd * 5; sh_h1T[(nd * 128 + h) * 20 + 4 + mm] = f2bf(v); }
                    }
                }
            }
        }
    }
    // No barrier: h1T rows h in [32w,32w+32) are wave-local (written+read by wave w).

    // ---- grid pipeline over node PAIRS (2 iterations, 2 nodes in flight each) ----
    for (int it = 0; it < 2; ++it) {
        // to_grid both nodes of the pair -> sh_g[0], sh_g[1]
        #pragma unroll
        for (int j = 0; j < 2; ++j) {
            const int nn = 2 * it + j;
            bf16x8 bfn = *(const bf16x8*)&sh_h1T[(nn * 128 + w * 32 + r32) * 20 + half * 8];
            f32x16 ac0, ac1;
            #pragma unroll
            for (int e = 0; e < 16; ++e) { ac0[e] = 0.f; ac1[e] = 0.f; }
            ac0 = __builtin_amdgcn_mfma_f32_32x32x16_bf16(tgA0, bfn, ac0, 0, 0, 0);
            ac1 = __builtin_amdgcn_mfma_f32_32x32x16_bf16(tgA1, bfn, ac1, 0, 0, 0);
            const int h = w * 32 + r32;
            #pragma unroll
            for (int rg = 0; rg < 16; ++rg) {
                const int ar = (rg & 3) + 8 * (rg >> 2) + 4 * half;
                sh_g[j][ar * 136 + h] = f2bf(ac0[rg]);
                const int ar1 = 32 + ar;
                if (ar1 < 48) sh_g[j][ar1 * 136 + h] = f2bf(ac1[rg]);
            }
        }
        __syncthreads();   // g[0],g[1] ready (it=0: also orders GEMM1 a1-reads vs h2b writes)

        // SwiGLU both nodes, SWAPPED operands (A=g-frag, B=gw-frag):
        //   z[a][o] = sum_h g[a][h] gw[o][h]  ->  C rows = a, cols = o
        // lane holds 4 consecutive a at fixed o -> packed b64 g2T writes.
        f32x4 sL[2][2][3], sH[2][2][3];   // [j][p][nt]
        #pragma unroll
        for (int j = 0; j < 2; ++j)
            #pragma unroll
            for (int p = 0; p < 2; ++p)
                #pragma unroll
                for (int nt = 0; nt < 3; ++nt)
                    #pragma unroll
                    for (int e = 0; e < 4; ++e) { sL[j][p][nt][e] = 0.f; sH[j][p][nt][e] = 0.f; }
        #pragma unroll
        for (int k = 0; k < 4; ++k) {
            bf16x8 bk[2][3];
            #pragma unroll
            for (int j = 0; j < 2; ++j)
                #pragma unroll
                for (int nt = 0; nt < 3; ++nt)
                    bk[j][nt] = *(const bf16x8*)&sh_g[j][(nt * 16 + r) * 136 + k * 32 + q * 8];
            #pragma unroll
            for (int p = 0; p < 2; ++p) {
                const int oL = (2 * w + p) * 16 + r;
                bf16x8 fL = *(const bf16x8*)&wsb[OFF_GW + oL * 128 + k * 32 + q * 8];
                bf16x8 fH = *(const bf16x8*)&wsb[OFF_GW + (oL + 128) * 128 + k * 32 + q * 8];
                #pragma unroll
                for (int j = 0; j < 2; ++j) {
                    #pragma unroll
                    for (int nt = 0; nt < 3; ++nt) {
                        sL[j][p][nt] = __builtin_amdgcn_mfma_f32_16x16x32_bf16(bk[j][nt], fL, sL[j][p][nt], 0, 0, 0);
                        sH[j][p][nt] = __builtin_amdgcn_mfma_f32_16x16x32_bf16(bk[j][nt], fH, sH[j][p][nt], 0, 0, 0);
                    }
                }
            }
        }
        if (it == 0) __syncthreads();  // all g reads complete -> next iter may overwrite sh_g

        // per node of the pair: silu -> g2T (wave-local rows o in [32w,32w+32)) -> from_grid -> h2b
        #pragma unroll
        for (int j = 0; j < 2; ++j) {
            const int nn = 2 * it + j;
            #pragma unroll
            for (int p = 0; p < 2; ++p) {
                const int o  = (2 * w + p) * 16 + r;
                const float bL = sh_gb[o];
                const float bH = sh_gb[128 + o];
                #pragma unroll
                for (int nt = 0; nt < 3; ++nt) {
                    float gv[4];
                    #pragma unroll
                    for (int rg = 0; rg < 4; ++rg) {
                        const float zl = sL[j][p][nt][rg] + bL;
                        const float zh = sH[j][p][nt][rg] + bH;
                        gv[rg] = zl * (1.0f / (1.0f + __expf(-zl))) * zh;
                    }
                    if (nt == 2) {   // a = 32 + q*4 + rg ; zero where a >= 42 (keeps pad zero)
                        #pragma unroll
                        for (int rg = 0; rg < 4; ++rg)
                            if (q * 4 + rg >= 10) gv[rg] = 0.f;
                    }
                    const unsigned pk0 = f2bf2(gv[0], gv[1]);
                    const unsigned pk1 = f2bf2(gv[2], gv[3]);
                    const int abase = nt * 16 + q * 4;
                    uint2* dst = (uint2*)__builtin_assume_aligned(&sh_g2T[o * 52 + abase], 8);
                    *dst = make_uint2(pk0, pk1);
                }
            }
            // from_grid (32x32x16, K=48, wave-local rows of g2T)
            {
                f32x16 ac;
                #pragma unroll
                for (int e = 0; e < 16; ++e) ac[e] = 0.f;
                const int h = w * 32 + r32;
                #pragma unroll
                for (int k = 0; k < 3; ++k) {
                    bf16x8 bv = *(const bf16x8*)&sh_g2T[h * 52 + k * 16 + half * 8];
                    ac = __builtin_amdgcn_mfma_f32_32x32x16_bf16(fgA[k], bv, ac, 0, 0, 0);
                }
                #pragma unroll
                for (int rg = 0; rg < 16; ++rg) {
                    const int m = (rg & 3) + 8 * (rg >> 2) + 4 * half;
                    if (m < 9) {
                        const int row = (m == 0) ? nn : ((m < 4) ? (16 + nn * 3 + (m - 1)) : (32 + nn * 5 + (m - 4)));
                        sh_a1[row * 136 + h] = f2bf(ac[rg]);
                    }
                }
            }
        }
    }
    __syncthreads();

    // ---- GEMM2 (batched, 16x16x32) + bias + unpack scatter store ----
    {
        f32x4 acc[4][2];
        #pragma unroll
        for (int a = 0; a < 4; ++a)
            #pragma unroll
            for (int b = 0; b < 2; ++b)
                #pragma unroll
                for (int e = 0; e < 4; ++e) acc[a][b][e] = 0.f;
        #pragma unroll
        for (int mt = 0; mt < 4; ++mt) {
            const int l = (mt == 0) ? 0 : ((mt == 1) ? 1 : 2);
            #pragma unroll
            for (int k = 0; k < 4; ++k) {
                bf16x8 af = *(const bf16x8*)&sh_a1[(mt * 16 + r) * 136 + k * 32 + q * 8];
                #pragma unroll
                for (int nt = 0; nt < 2; ++nt) {
                    const int c = (2 * w + nt) * 16 + r;
                    bf16x8 bf = *(const bf16x8*)&wsb[OFF_W2 + (l * 128 + c) * 128 + k * 32 + q * 8];
                    acc[mt][nt] = __builtin_amdgcn_mfma_f32_16x16x32_bf16(af, bf, acc[mt][nt], 0, 0, 0);
                }
            }
        }
        #pragma unroll
        for (int mt = 0; mt < 4; ++mt) {
            #pragma unroll
            for (int nt = 0; nt < 2; ++nt) {
                const int c = (2 * w + nt) * 16 + r;
                #pragma unroll
                for (int rg = 0; rg < 4; ++rg) {
                    const int rr = q * 4 + rg;
                    const float v = acc[mt][nt][rg];
                    if (mt == 0) {
                        if (rr < 4) { int gn = n0 + rr; if (gn < N) out[(size_t)gn * 1152 + c] = v + sh_b2[c]; }
                    } else if (mt == 1) {
                        if (rr < 12) { int nd = rr / 3, mm = rr - nd * 3; int gn = n0 + nd;
                                       if (gn < N) out[(size_t)gn * 1152 + 128 + c * 3 + mm] = v; }
                    } else {
                        int rr2 = (mt - 2) * 16 + rr;
                        if (rr2 < 20) { int nd = rr2 / 5, mm = rr2 - nd * 5; int gn = n0 + nd;
                                        if (gn < N) out[(size_t)gn * 1152 + 512 + c * 5 + mm] = v; }
                    }
                }
            }
        }
    }
}

extern "C" void kernel_launch(void* const* d_in, const int* in_sizes, int n_in,
                              void* d_out, int out_size, void* d_ws, size_t ws_size,
                              hipStream_t stream)
{
    const float* x  = (const float*)d_in[0];
    const float* nw = (const float*)d_in[1];
    const float* w1 = (const float*)d_in[2];
    const float* b1 = (const float*)d_in[3];
    const float* gw = (const float*)d_in[4];
    const float* gb = (const float*)d_in[5];
    const float* w2 = (const float*)d_in[6];
    const float* b2 = (const float*)d_in[7];
    const float* tg = (const float*)d_in[8];
    const float* fg = (const float*)d_in[9];
    float* out = (float*)d_out;
    u16* wsb = (u16*)d_ws;

    const int N = in_sizes[0] / 1152;
    prep_kernel<<<64, 256, 0, stream>>>(w1, gw, w2, tg, fg, wsb);
    eqffn_mfma<<<(N + 3) / 4, 256, 0, stream>>>(x, nw, b1, gb, b2, wsb, out, N);
}